// Round 6
// baseline (366.125 us; speedup 1.0000x reference)
//
#include <hip/hip_runtime.h>
#include <hip/hip_cooperative_groups.h>
#include <hip/hip_bf16.h>
#include <stdint.h>

namespace cg = cooperative_groups;

// Problem constants (UniformStrideAttention): B=2, S=2048, D=768, H=12, HD=64, STRIDE=8
#define H_   12
#define S_   2048
#define D_   768
#define HD_  64
#define MS_  256   // S_/8 compressed strided keys per head

// ws element counts
constexpr int NXc  = 2 * S_ * D_;        // 3,145,728  (x / q / k / vt / ctx)
constexpr int NW1c = 3 * D_ * D_;        // 1,769,472  (qkv_w)
constexpr int NW2c = D_ * D_;            //   589,824  (out_w)
constexpr int NVSc = 2 * H_ * HD_ * MS_; //   393,216  (vst)

typedef __bf16 bf16_8 __attribute__((ext_vector_type(8)));
typedef float  f32_4  __attribute__((ext_vector_type(4)));

typedef __attribute__((address_space(1))) void* gas_ptr;
typedef __attribute__((address_space(3))) void* las_ptr;

__device__ __forceinline__ void g2l16(const void* g, void* l) {
  __builtin_amdgcn_global_load_lds((gas_ptr)g, (las_ptr)l, 16, 0, 0);
}

__device__ __forceinline__ f32_4 mfma16(bf16_8 a, bf16_8 b, f32_4 c) {
  return __builtin_amdgcn_mfma_f32_16x16x32_bf16(a, b, c, 0, 0, 0);
}

__device__ __forceinline__ bf16_8 ld8(const __hip_bfloat16* p) {
  return *reinterpret_cast<const bf16_8*>(p);
}

// ---------------------------------------------------------------------------
// Phase 0: fp32 -> bf16 convert of x|qkv_w|out_w into contiguous ws region.
// ---------------------------------------------------------------------------
__device__ __forceinline__ void cvt_phase(
    const float* x, const float* w1, const float* w2, __hip_bfloat16* dst) {
  constexpr int na4 = NXc / 4, nb4 = NW1c / 4, nc4 = NW2c / 4;
  const int T = gridDim.x * 256;
  for (int t = blockIdx.x * 256 + threadIdx.x; t < na4 + nb4 + nc4; t += T) {
    float4 f;
    if (t < na4)            f = reinterpret_cast<const float4*>(x)[t];
    else if (t < na4 + nb4) f = reinterpret_cast<const float4*>(w1)[t - na4];
    else                    f = reinterpret_cast<const float4*>(w2)[t - na4 - nb4];
    union { __hip_bfloat16 h[4]; ushort4 u; } p;
    p.h[0] = __float2bfloat16(f.x);
    p.h[1] = __float2bfloat16(f.y);
    p.h[2] = __float2bfloat16(f.z);
    p.h[3] = __float2bfloat16(f.w);
    reinterpret_cast<ushort4*>(dst)[t] = p.u;
  }
}

// ---------------------------------------------------------------------------
// GEMM tile: C[128,BN] = A[128,768] * B[BN,768]^T + bias (m97 structure).
// MODE 0 (BN=128): QKV epilogue -> q[bh][s][d], k[bh][s][d], VT[bh][d][s],
//                  VsT[bh][d][s/8].   MODE 1: plain fp32 epilogue.
// ---------------------------------------------------------------------------
template <int MODE, int BN>
__device__ __forceinline__ void gemm_tile(
    const __hip_bfloat16* A, const __hip_bfloat16* B, const float* bias,
    __hip_bfloat16* O0, __hip_bfloat16* O1, __hip_bfloat16* O2,
    __hip_bfloat16* O3, float* OF, int m0, int n0, __bf16* sA, __bf16* sB) {
  constexpr int K   = 768;
  constexpr int NTJ = BN / 32;
  const int tid  = threadIdx.x;
  const int lane = tid & 63;
  const int wv   = tid >> 6;
  const int wr = (wv >> 1) * 64;
  const int wc = (wv & 1) * (BN / 2);

  f32_4 acc[4][NTJ] = {};

  const __hip_bfloat16* aS = A + (size_t)(m0 + (tid >> 2)) * K + ((tid & 3) << 3);
  const __hip_bfloat16* bS = B + (size_t)(n0 + (tid >> 2)) * K + ((tid & 3) << 3);
  const size_t half = (size_t)64 * K;
  __bf16* dA  = sA + tid * 8;
  __bf16* dA2 = sA + tid * 8 + 2048;
  __bf16* dB  = sB + tid * 8;
  __bf16* dB2 = sB + tid * 8 + 2048;

  const int fr = lane & 15;
  const int kq = (lane >> 4) << 3;

  for (int k0 = 0; k0 < K; k0 += 32) {
    g2l16(aS, dA);
    g2l16(aS + half, dA2);
    g2l16(bS, dB);
    if constexpr (BN == 128) g2l16(bS + half, dB2);
    aS += 32;
    bS += 32;
    __syncthreads();
    bf16_8 af[4], bfm[NTJ];
#pragma unroll
    for (int t = 0; t < 4; ++t)
      af[t] = *reinterpret_cast<const bf16_8*>(sA + (wr + t * 16 + fr) * 32 + kq);
#pragma unroll
    for (int t = 0; t < NTJ; ++t)
      bfm[t] = *reinterpret_cast<const bf16_8*>(sB + (wc + t * 16 + fr) * 32 + kq);
#pragma unroll
    for (int ti = 0; ti < 4; ++ti)
#pragma unroll
      for (int tj = 0; tj < NTJ; ++tj)
        acc[ti][tj] = mfma16(af[ti], bfm[tj], acc[ti][tj]);
    __syncthreads();   // also guards LDS before next tile's staging
  }

  // epilogue: C/D layout col=lane&15, row=(lane>>4)*4+reg
  const int crow = (lane >> 4) << 2;
  const int ccol = lane & 15;
#pragma unroll
  for (int ti = 0; ti < 4; ++ti) {
    const int gmb = m0 + wr + ti * 16 + crow;
#pragma unroll
    for (int tj = 0; tj < NTJ; ++tj) {
      const int gn = n0 + wc + tj * 16 + ccol;
      const float bv = bias[gn];
      if (MODE == 0) {
        const int t   = gn / D_;
        const int rem = gn - t * D_;
        const int hh = rem >> 6, dd = rem & 63;
        if (t < 2) {
          __hip_bfloat16* dst = (t == 0) ? O0 : O1;
#pragma unroll
          for (int r = 0; r < 4; ++r) {
            const int gm = gmb + r;
            const int bb = gm >> 11, ss = gm & (S_ - 1);
            dst[(((size_t)(bb * H_ + hh) << 11) + ss) * HD_ + dd] =
                __float2bfloat16(acc[ti][tj][r] + bv);
          }
        } else {
          // v -> VT[bh][d][s] (+ VsT for s%8==0); 4 rows contiguous in s
          const int bb = gmb >> 11, ss = gmb & (S_ - 1);
          union { ushort4 u; __hip_bfloat16 h[4]; } pk;
#pragma unroll
          for (int r = 0; r < 4; ++r) pk.h[r] = __float2bfloat16(acc[ti][tj][r] + bv);
          const size_t rowb = ((size_t)(bb * H_ + hh) * HD_ + dd);
          *reinterpret_cast<ushort4*>(O2 + rowb * S_ + ss) = pk.u;  // 8B aligned
          if ((ss & 7) == 0) O3[rowb * MS_ + (ss >> 3)] = pk.h[0];
        }
      } else {
#pragma unroll
        for (int r = 0; r < 4; ++r)
          OF[(size_t)(gmb + r) * D_ + gn] = acc[ti][tj][r] + bv;
      }
    }
  }
}

// ---------------------------------------------------------------------------
// Phase 2: MFMA strided attention, NO-RESCALE softmax (R5 numerics verbatim).
// mask = (j%8==0 && j<=i) | j==i | j==i-1; strided part = causal over
// compressed keys (j=8m), local band chunk {i-1,i}\{mult of 8} last.
// One wave per (head, 16 query rows); per chunk 4 QK^T + 4 PV + 1 ones MFMA;
// L rides the matrix pipe (P.1); P C->A layout via per-wave LDS tile.
// ---------------------------------------------------------------------------
__device__ void attn_task(
    const __hip_bfloat16* Q, const __hip_bfloat16* Kb,
    const __hip_bfloat16* VT, const __hip_bfloat16* VsT,
    __hip_bfloat16* ctx, int task, __bf16* ptw) {
  const int lane = threadIdx.x & 63;
  const int bh   = task >> 7;
  const int i0   = (task & 127) << 4;
  const int lr   = lane & 15;
  const int quad = lane >> 4;
  const float SC = 0.125f * 1.44269504088896340736f;  // 1/sqrt(64)*log2(e)

  const __hip_bfloat16* Kh  = Kb  + ((size_t)bh << 11) * HD_;
  const __hip_bfloat16* VTh = VT  + (size_t)bh * HD_ * S_;
  const __hip_bfloat16* Vsh = VsT + (size_t)bh * HD_ * MS_;

  const __hip_bfloat16* qp = Q + (((size_t)bh << 11) + i0 + lr) * HD_ + quad * 8;
  const bf16_8 qf0 = ld8(qp);
  const bf16_8 qf1 = ld8(qp + 32);

  const __bf16 one = (__bf16)1.0f;
  const bf16_8 onesf = {one, one, one, one, one, one, one, one};

  f32_4 Lacc = {}, oacc[4];
#pragma unroll
  for (int ct = 0; ct < 4; ++ct) oacc[ct] = f32_4{0.f, 0.f, 0.f, 0.f};

  const int mmax = (i0 + 15) >> 3;
  const int nstr = (mmax >> 5) + 1;
  for (int c = 0; c <= nstr; ++c) {
    const bool strided = (c < nstr);
    const int  mb    = c << 5;
    const int  jbase = (i0 >= 8) ? (i0 - 8) : 0;

    bf16_8 kf[2][2], vf[4];
    if (strided) {
#pragma unroll
      for (int t = 0; t < 2; ++t) {
        const int m = mb + t * 16 + lr;
        const __hip_bfloat16* kp = Kh + ((size_t)m << 3) * HD_ + quad * 8;
        kf[t][0] = ld8(kp);
        kf[t][1] = ld8(kp + 32);
      }
#pragma unroll
      for (int ct = 0; ct < 4; ++ct)
        vf[ct] = ld8(Vsh + (size_t)(ct * 16 + lr) * MS_ + mb + quad * 8);
    } else {
#pragma unroll
      for (int t = 0; t < 2; ++t) {
        const int j  = jbase + t * 16 + lr;
        const int jr = (j < S_) ? j : (S_ - 1);
        const __hip_bfloat16* kp = Kh + (size_t)jr * HD_ + quad * 8;
        kf[t][0] = ld8(kp);
        kf[t][1] = ld8(kp + 32);
      }
      const int vs0 = jbase + quad * 8;
      const int vs  = (vs0 <= S_ - 8) ? vs0 : (S_ - 8);
#pragma unroll
      for (int ct = 0; ct < 4; ++ct)
        vf[ct] = ld8(VTh + (size_t)(ct * 16 + lr) * S_ + vs);
    }

    f32_4 s0 = {}, s1 = {};
    s0 = mfma16(qf0, kf[0][0], s0);
    s0 = mfma16(qf1, kf[0][1], s0);
    s1 = mfma16(qf0, kf[1][0], s1);
    s1 = mfma16(qf1, kf[1][1], s1);

#pragma unroll
    for (int r = 0; r < 4; ++r) {
      const int i = i0 + quad * 4 + r;
      bool v0, v1;
      if (strided) {
        v0 = ((mb + lr) << 3) <= i;
        v1 = ((mb + 16 + lr) << 3) <= i;
      } else {
        const int j0 = jbase + lr, j1 = jbase + 16 + lr;
        v0 = (j0 == i || j0 == i - 1) && (j0 & 7);
        v1 = (j1 == i || j1 == i - 1) && (j1 & 7);
      }
      s0[r] = v0 ? exp2f(fminf(s0[r] * SC, 63.f)) : 0.f;
      s1[r] = v1 ? exp2f(fminf(s1[r] * SC, 63.f)) : 0.f;
    }

#pragma unroll
    for (int r = 0; r < 4; ++r) {
      const int row = quad * 4 + r;
      ptw[row * 40 + lr]      = (__bf16)__float2bfloat16(s0[r]);
      ptw[row * 40 + 16 + lr] = (__bf16)__float2bfloat16(s1[r]);
    }
    const bf16_8 pf = *reinterpret_cast<const bf16_8*>(ptw + lr * 40 + quad * 8);

#pragma unroll
    for (int ct = 0; ct < 4; ++ct) oacc[ct] = mfma16(pf, vf[ct], oacc[ct]);
    Lacc = mfma16(pf, onesf, Lacc);
  }

  const int b = bh / H_;
  const int h = bh - b * H_;
  f32_4 inv;
#pragma unroll
  for (int r = 0; r < 4; ++r) inv[r] = 1.f / Lacc[r];
#pragma unroll
  for (int r = 0; r < 4; ++r) {
    const int i = i0 + quad * 4 + r;
    __hip_bfloat16* cp = ctx + ((size_t)(b * S_ + i)) * D_ + h * HD_ + lr;
#pragma unroll
    for (int ct = 0; ct < 4; ++ct)
      cp[ct * 16] = __float2bfloat16(oacc[ct][r] * inv[r]);
  }
}

// ---------------------------------------------------------------------------
// Mega-kernel: cvt -> gridsync -> QKV GEMM -> gridsync -> attn -> gridsync
// -> out GEMM.  Persistent cooperative grid (512 blocks @ 2/CU), grid-stride
// task loops per phase. Saves 3 launch+drain overheads vs 4 dispatches.
// ---------------------------------------------------------------------------
__global__ __launch_bounds__(256, 2) void mega(
    const float* __restrict__ x, const float* __restrict__ qkvw,
    const float* __restrict__ qkvb, const float* __restrict__ outw,
    const float* __restrict__ outb, float* out, __hip_bfloat16* ws) {
  __shared__ __bf16 sA[128 * 32];
  __shared__ __bf16 sB[128 * 32];

  __hip_bfloat16* xb  = ws;
  __hip_bfloat16* w1b = xb + NXc;
  __hip_bfloat16* w2b = w1b + NW1c;
  __hip_bfloat16* q   = w2b + NW2c;
  __hip_bfloat16* k   = q + NXc;
  __hip_bfloat16* vt  = k + NXc;     // [bh][64][2048]
  __hip_bfloat16* vst = vt + NXc;    // [bh][64][256]
  __hip_bfloat16* ctx = vst + NVSc;  // [B,S,H*HD]

  cg::grid_group grid = cg::this_grid();

  // phase 0: converts
  cvt_phase(x, qkvw, outw, xb);
  __threadfence();
  grid.sync();

  // phase 1: QKV GEMM, 18x32 = 576 tiles
  for (int t = blockIdx.x; t < 576; t += gridDim.x)
    gemm_tile<0, 128>(xb, w1b, qkvb, q, k, vt, vst, nullptr,
                      (t / 18) * 128, (t % 18) * 128, sA, sB);
  __threadfence();
  grid.sync();

  // phase 2: attention, 768 block-tasks (4 wave-tasks each)
  {
    const int wv = threadIdx.x >> 6;
    for (int bt = blockIdx.x; bt < 768; bt += gridDim.x)
      attn_task(q, k, vt, vst, ctx, bt * 4 + wv, sA + wv * 640);
  }
  __threadfence();
  grid.sync();

  // phase 3: out GEMM, 12x32 = 384 tiles (BN=64)
  for (int t = blockIdx.x; t < 384; t += gridDim.x)
    gemm_tile<1, 64>(ctx, w2b, outb, nullptr, nullptr, nullptr, nullptr, out,
                     (t / 12) * 128, (t % 12) * 64, sA, sB);
}

// ---------------------------------------------------------------------------
extern "C" void kernel_launch(void* const* d_in, const int* in_sizes, int n_in,
                              void* d_out, int out_size, void* d_ws, size_t ws_size,
                              hipStream_t stream) {
  const float* x    = (const float*)d_in[0];  // [B,S,D]    fp32
  const float* qkvw = (const float*)d_in[1];  // [3D,D]     fp32
  const float* qkvb = (const float*)d_in[2];  // [3D]       fp32
  const float* outw = (const float*)d_in[3];  // [D,D]      fp32
  const float* outb = (const float*)d_in[4];  // [D]        fp32
  float* out = (float*)d_out;                 // [B,S,D]    fp32
  __hip_bfloat16* ws = (__hip_bfloat16*)d_ws; // ~36.5 MB used

  // grid = min(512, occupancy-capacity); all phases are grid-stride so any
  // grid size is correct. __launch_bounds__(256,2) targets 2 blocks/CU -> 512.
  int nb = 0;
  if (hipOccupancyMaxActiveBlocksPerMultiprocessor(&nb, mega, 256, 0) != hipSuccess
      || nb < 1)
    nb = 1;
  int gsz = nb * 256;
  if (gsz > 512) gsz = 512;

  void* args[] = {(void*)&x, (void*)&qkvw, (void*)&qkvb, (void*)&outw,
                  (void*)&outb, (void*)&out, (void*)&ws};
  hipLaunchCooperativeKernel(mega, dim3(gsz), dim3(256), args, 0, stream);
}

// Round 7
// 151.861 us; speedup vs baseline: 2.4109x; 2.4109x over previous
//
#include <hip/hip_runtime.h>
#include <hip/hip_bf16.h>
#include <stdint.h>

// Problem constants (UniformStrideAttention): B=2, S=2048, D=768, H=12, HD=64, STRIDE=8
#define H_   12
#define S_   2048
#define D_   768
#define HD_  64
#define MS_  256   // S_/8 compressed strided keys per head

typedef __bf16 bf16_8 __attribute__((ext_vector_type(8)));
typedef float  f32_4  __attribute__((ext_vector_type(4)));

typedef __attribute__((address_space(1))) void* gas_ptr;
typedef __attribute__((address_space(3))) void* las_ptr;

__device__ __forceinline__ void g2l16(const void* g, void* l) {
  __builtin_amdgcn_global_load_lds((gas_ptr)g, (las_ptr)l, 16, 0, 0);
}

__device__ __forceinline__ f32_4 mfma16(bf16_8 a, bf16_8 b, f32_4 c) {
  return __builtin_amdgcn_mfma_f32_16x16x32_bf16(a, b, c, 0, 0, 0);
}

__device__ __forceinline__ bf16_8 ld8(const __hip_bfloat16* p) {
  return *reinterpret_cast<const bf16_8*>(p);
}

// ---------------------------------------------------------------------------
// Fused fp32 -> bf16 convert for all three GEMM inputs (x, qkv_w, out_w).
// Destinations are CONTIGUOUS in ws (xb | w1b | w2b), so output index == t.
// ---------------------------------------------------------------------------
__global__ __launch_bounds__(256) void cvt3_f32_bf16(
    const float* __restrict__ a, const float* __restrict__ b,
    const float* __restrict__ c, __hip_bfloat16* __restrict__ out,
    int na4, int nb4) {
  const int t = blockIdx.x * 256 + threadIdx.x;
  float4 f;
  if (t < na4)            f = reinterpret_cast<const float4*>(a)[t];
  else if (t < na4 + nb4) f = reinterpret_cast<const float4*>(b)[t - na4];
  else                    f = reinterpret_cast<const float4*>(c)[t - na4 - nb4];
  union { __hip_bfloat16 h[4]; ushort4 u; } p;
  p.h[0] = __float2bfloat16(f.x);
  p.h[1] = __float2bfloat16(f.y);
  p.h[2] = __float2bfloat16(f.z);
  p.h[3] = __float2bfloat16(f.w);
  reinterpret_cast<ushort4*>(out)[t] = p.u;
}

// ---------------------------------------------------------------------------
// C[M,N] = A[M,K] * B[N,K]^T + bias[N]   (bf16 in, fp32 MFMA accum, fp32 bias)
// Tile 128 x BN, BK=32; 4 waves as 2x2 of 64 x BN/2; 16x16x32 MFMA.
// MODE 0 (BN=128): QKV epilogue -> q[bh][s][d], k[bh][s][d] (+ compressed
//   Ks[bh][s/8][d] for s%8==0), VT[bh][d][s], VsT[bh][d][s/8].
// MODE 1: plain epilogue -> OF[M,N] fp32. BN=64: 2x grid for small N.
// ---------------------------------------------------------------------------
template <int MODE, int BN>
__global__ __launch_bounds__(256, 2) void gemm_bt(
    const __hip_bfloat16* __restrict__ A, const __hip_bfloat16* __restrict__ B,
    const float* __restrict__ bias,
    __hip_bfloat16* __restrict__ O0, __hip_bfloat16* __restrict__ O1,
    __hip_bfloat16* __restrict__ O2, __hip_bfloat16* __restrict__ O3,
    __hip_bfloat16* __restrict__ O4, float* __restrict__ OF,
    int M, int N, int K) {
  constexpr int NTJ = BN / 32;          // B col-tiles per wave
  __shared__ __bf16 sA[128 * 32];
  __shared__ __bf16 sB[BN * 32];
  const int tid  = threadIdx.x;
  const int lane = tid & 63;
  const int wv   = tid >> 6;
  const int m0 = blockIdx.y * 128;
  const int n0 = blockIdx.x * BN;
  const int wr = (wv >> 1) * 64;
  const int wc = (wv & 1) * (BN / 2);

  f32_4 acc[4][NTJ] = {};

  const __hip_bfloat16* aS = A + (size_t)(m0 + (tid >> 2)) * K + ((tid & 3) << 3);
  const __hip_bfloat16* bS = B + (size_t)(n0 + (tid >> 2)) * K + ((tid & 3) << 3);
  const size_t half = (size_t)64 * K;
  __bf16* dA  = &sA[tid * 8];
  __bf16* dA2 = &sA[tid * 8 + 2048];
  __bf16* dB  = &sB[tid * 8];
  __bf16* dB2 = &sB[tid * 8 + 2048];

  const int fr = lane & 15;
  const int kq = (lane >> 4) << 3;

  for (int k0 = 0; k0 < K; k0 += 32) {
    g2l16(aS, dA);
    g2l16(aS + half, dA2);
    g2l16(bS, dB);
    if constexpr (BN == 128) g2l16(bS + half, dB2);
    aS += 32;
    bS += 32;
    __syncthreads();
    bf16_8 af[4], bfm[NTJ];
#pragma unroll
    for (int t = 0; t < 4; ++t)
      af[t] = *reinterpret_cast<const bf16_8*>(&sA[(wr + t * 16 + fr) * 32 + kq]);
#pragma unroll
    for (int t = 0; t < NTJ; ++t)
      bfm[t] = *reinterpret_cast<const bf16_8*>(&sB[(wc + t * 16 + fr) * 32 + kq]);
#pragma unroll
    for (int ti = 0; ti < 4; ++ti)
#pragma unroll
      for (int tj = 0; tj < NTJ; ++tj)
        acc[ti][tj] = mfma16(af[ti], bfm[tj], acc[ti][tj]);
    __syncthreads();
  }

  // epilogue: C/D layout col=lane&15, row=(lane>>4)*4+reg
  const int crow = (lane >> 4) << 2;
  const int ccol = lane & 15;
#pragma unroll
  for (int ti = 0; ti < 4; ++ti) {
    const int gmb = m0 + wr + ti * 16 + crow;
#pragma unroll
    for (int tj = 0; tj < NTJ; ++tj) {
      const int gn = n0 + wc + tj * 16 + ccol;
      const float bv = bias[gn];
      if (MODE == 0) {
        const int t   = gn / D_;
        const int rem = gn - t * D_;
        const int hh = rem >> 6, dd = rem & 63;
        if (t < 2) {
          __hip_bfloat16* dst = (t == 0) ? O0 : O1;
#pragma unroll
          for (int r = 0; r < 4; ++r) {
            const int gm = gmb + r;
            const int bb = gm >> 11, ss = gm & (S_ - 1);
            const __hip_bfloat16 hv = __float2bfloat16(acc[ti][tj][r] + bv);
            dst[(((size_t)(bb * H_ + hh) << 11) + ss) * HD_ + dd] = hv;
            // compressed K rows (s%8==0) for coalesced strided-attention reads
            if (t == 1 && r == 0 && (gmb & 7) == 0)
              O4[(((size_t)(bb * H_ + hh)) * MS_ + (ss >> 3)) * HD_ + dd] = hv;
          }
        } else {
          // v -> VT[bh][d][s] (+ VsT for s%8==0); 4 rows contiguous in s
          const int bb = gmb >> 11, ss = gmb & (S_ - 1);
          union { ushort4 u; __hip_bfloat16 h[4]; } pk;
#pragma unroll
          for (int r = 0; r < 4; ++r) pk.h[r] = __float2bfloat16(acc[ti][tj][r] + bv);
          const size_t rowb = ((size_t)(bb * H_ + hh) * HD_ + dd);
          *reinterpret_cast<ushort4*>(O2 + rowb * S_ + ss) = pk.u;  // 8B aligned
          if ((ss & 7) == 0) O3[rowb * MS_ + (ss >> 3)] = pk.h[0];
        }
      } else {
#pragma unroll
        for (int r = 0; r < 4; ++r)
          OF[(size_t)(gmb + r) * D_ + gn] = acc[ti][tj][r] + bv;
      }
    }
  }
}

// ---------------------------------------------------------------------------
// MFMA strided attention, NO-RESCALE softmax + chunk PREFETCH.
// mask = (j%8==0 && j<=i) | j==i | j==i-1; strided part = causal over
// compressed keys (j=8m, Ks/VsT buffers -> fully coalesced 16B-lane reads),
// local band chunk {i-1,i}\{mult of 8} is the last chunk.
// One wave per (head, 16 query rows); per chunk 4 QK^T + 4 PV + 1 ones MFMA;
// L rides the matrix pipe (P.1); P C->A layout via per-wave LDS tile.
// Next chunk's K/V fragments are loaded BEFORE computing the current chunk,
// so global-load latency overlaps the MFMA/exp2/LDS chain.
// ---------------------------------------------------------------------------
__global__ __launch_bounds__(256) void attn_mfma(
    const __hip_bfloat16* __restrict__ Q, const __hip_bfloat16* __restrict__ Kb,
    const __hip_bfloat16* __restrict__ Ks, const __hip_bfloat16* __restrict__ VT,
    const __hip_bfloat16* __restrict__ VsT, __hip_bfloat16* __restrict__ ctx) {
  __shared__ __bf16 pt[4][16 * 40];
  const int lane = threadIdx.x & 63;
  const int wv   = threadIdx.x >> 6;
  const int task = blockIdx.x * 4 + wv;     // 3072 tasks = bh*128 + qtile
  const int bh   = task >> 7;
  const int i0   = (task & 127) << 4;       // first of 16 query rows
  const int lr   = lane & 15;
  const int quad = lane >> 4;
  const float SC = 0.125f * 1.44269504088896340736f;  // 1/sqrt(64)*log2(e)

  const __hip_bfloat16* Kh  = Kb  + ((size_t)bh << 11) * HD_;
  const __hip_bfloat16* Ksh = Ks  + (size_t)bh * MS_ * HD_;
  const __hip_bfloat16* VTh = VT  + (size_t)bh * HD_ * S_;
  const __hip_bfloat16* Vsh = VsT + (size_t)bh * HD_ * MS_;
  __bf16* ptw = pt[wv];

  // Q A-frags: row = i0+lr, k = quad*8 (+32) — held all kernel
  const __hip_bfloat16* qp = Q + (((size_t)bh << 11) + i0 + lr) * HD_ + quad * 8;
  const bf16_8 qf0 = ld8(qp);
  const bf16_8 qf1 = ld8(qp + 32);

  const __bf16 one = (__bf16)1.0f;
  const bf16_8 onesf = {one, one, one, one, one, one, one, one};

  f32_4 Lacc = {}, oacc[4];
#pragma unroll
  for (int ct = 0; ct < 4; ++ct) oacc[ct] = f32_4{0.f, 0.f, 0.f, 0.f};

  const int mmax  = (i0 + 15) >> 3;
  const int nstr  = (mmax >> 5) + 1;  // strided chunks; then one local chunk
  const int jbase = (i0 >= 8) ? (i0 - 8) : 0;   // local band base (8-aligned)

  auto load_chunk = [&](int c, bf16_8 (&kf)[2][2], bf16_8 (&vf)[4]) {
    if (c < nstr) {   // strided: compressed Ks/VsT, fully coalesced
      const int mb = c << 5;
#pragma unroll
      for (int t = 0; t < 2; ++t) {
        const __hip_bfloat16* kp = Ksh + (size_t)(mb + t * 16 + lr) * HD_ + quad * 8;
        kf[t][0] = ld8(kp);
        kf[t][1] = ld8(kp + 32);
      }
#pragma unroll
      for (int ct = 0; ct < 4; ++ct)
        vf[ct] = ld8(Vsh + (size_t)(ct * 16 + lr) * MS_ + mb + quad * 8);
    } else {          // local band
#pragma unroll
      for (int t = 0; t < 2; ++t) {
        const int j  = jbase + t * 16 + lr;
        const int jr = (j < S_) ? j : (S_ - 1);    // clamp; masked anyway
        const __hip_bfloat16* kp = Kh + (size_t)jr * HD_ + quad * 8;
        kf[t][0] = ld8(kp);
        kf[t][1] = ld8(kp + 32);
      }
      const int vs0 = jbase + quad * 8;
      const int vs  = (vs0 <= S_ - 8) ? vs0 : (S_ - 8);
#pragma unroll
      for (int ct = 0; ct < 4; ++ct)
        vf[ct] = ld8(VTh + (size_t)(ct * 16 + lr) * S_ + vs);
    }
  };

  bf16_8 kf[2][2], vf[4], kf2[2][2], vf2[4];
  load_chunk(0, kf, vf);

  for (int c = 0; c <= nstr; ++c) {
    if (c < nstr) load_chunk(c + 1, kf2, vf2);   // prefetch next chunk

    const bool strided = (c < nstr);
    const int  mb      = c << 5;

    // --- scores ---
    f32_4 s0 = {}, s1 = {};
    s0 = mfma16(qf0, kf[0][0], s0);
    s0 = mfma16(qf1, kf[0][1], s0);
    s1 = mfma16(qf0, kf[1][0], s1);
    s1 = mfma16(qf1, kf[1][1], s1);

    // --- mask + scale + exp2 (no max subtraction; clamp for safety) ---
#pragma unroll
    for (int r = 0; r < 4; ++r) {
      const int i = i0 + quad * 4 + r;
      bool v0, v1;
      if (strided) {
        v0 = ((mb + lr) << 3) <= i;
        v1 = ((mb + 16 + lr) << 3) <= i;
      } else {
        const int j0 = jbase + lr, j1 = jbase + 16 + lr;
        v0 = (j0 == i || j0 == i - 1) && (j0 & 7);
        v1 = (j1 == i || j1 == i - 1) && (j1 & 7);
      }
      s0[r] = v0 ? exp2f(fminf(s0[r] * SC, 63.f)) : 0.f;
      s1[r] = v1 ? exp2f(fminf(s1[r] * SC, 63.f)) : 0.f;
    }

    // --- P: C-layout -> A-layout via per-wave LDS tile ---
#pragma unroll
    for (int r = 0; r < 4; ++r) {
      const int row = quad * 4 + r;
      ptw[row * 40 + lr]      = (__bf16)__float2bfloat16(s0[r]);
      ptw[row * 40 + 16 + lr] = (__bf16)__float2bfloat16(s1[r]);
    }
    const bf16_8 pf = *reinterpret_cast<const bf16_8*>(&ptw[lr * 40 + quad * 8]);

    // --- PV and L += P.1 ---
#pragma unroll
    for (int ct = 0; ct < 4; ++ct) oacc[ct] = mfma16(pf, vf[ct], oacc[ct]);
    Lacc = mfma16(pf, onesf, Lacc);

    // rotate prefetched fragments in
    if (c < nstr) {
#pragma unroll
      for (int t = 0; t < 2; ++t) { kf[t][0] = kf2[t][0]; kf[t][1] = kf2[t][1]; }
#pragma unroll
      for (int ct = 0; ct < 4; ++ct) vf[ct] = vf2[ct];
    }
  }

  // --- epilogue: o/l -> ctx[b][s][h*64+d] ---
  const int b = bh / H_;
  const int h = bh - b * H_;
  f32_4 inv;
#pragma unroll
  for (int r = 0; r < 4; ++r) inv[r] = 1.f / Lacc[r];
#pragma unroll
  for (int r = 0; r < 4; ++r) {
    const int i = i0 + quad * 4 + r;
    __hip_bfloat16* cp = ctx + ((size_t)(b * S_ + i)) * D_ + h * HD_ + lr;
#pragma unroll
    for (int ct = 0; ct < 4; ++ct)
      cp[ct * 16] = __float2bfloat16(oacc[ct][r] * inv[r]);
  }
}

// ---------------------------------------------------------------------------
extern "C" void kernel_launch(void* const* d_in, const int* in_sizes, int n_in,
                              void* d_out, int out_size, void* d_ws, size_t ws_size,
                              hipStream_t stream) {
  const float* x    = (const float*)d_in[0];  // [B,S,D]    fp32
  const float* qkvw = (const float*)d_in[1];  // [3D,D]     fp32
  const float* qkvb = (const float*)d_in[2];  // [3D]       fp32
  const float* outw = (const float*)d_in[3];  // [D,D]      fp32
  const float* outb = (const float*)d_in[4];  // [D]        fp32
  float* out = (float*)d_out;                 // [B,S,D]    fp32

  const size_t NX  = (size_t)2 * S_ * D_;     // 3,145,728
  const size_t NW1 = (size_t)3 * D_ * D_;     // 1,769,472
  const size_t NW2 = (size_t)D_ * D_;         //   589,824
  const size_t NVS = (size_t)2 * H_ * HD_ * MS_;  // 393,216

  __hip_bfloat16* xb  = (__hip_bfloat16*)d_ws;
  __hip_bfloat16* w1b = xb + NX;
  __hip_bfloat16* w2b = w1b + NW1;
  __hip_bfloat16* q   = w2b + NW2;
  __hip_bfloat16* k   = q + NX;
  __hip_bfloat16* vt  = k + NX;     // [bh][64][2048]
  __hip_bfloat16* vst = vt + NX;    // [bh][64][256]
  __hip_bfloat16* ks  = vst + NVS;  // [bh][256][64] compressed K rows
  __hip_bfloat16* ctx = ks + NVS;   // [B,S,H*HD]
  // total ws: (5*NX + NW1 + NW2 + 2*NVS)*2 B ~= 37.3 MB

  // fused fp32 -> bf16 converts (xb|w1b|w2b contiguous)
  const int na4 = (int)(NX / 4), nb4 = (int)(NW1 / 4), nc4 = (int)(NW2 / 4);
  cvt3_f32_bf16<<<dim3((na4 + nb4 + nc4) / 256), 256, 0, stream>>>(
      x, qkvw, outw, xb, na4, nb4);

  gemm_bt<0, 128><<<dim3(2304 / 128, 4096 / 128), 256, 0, stream>>>(
      xb, w1b, qkvb, q, k, vt, vst, ks, nullptr, 4096, 2304, 768);

  attn_mfma<<<dim3(2 * H_ * S_ / 16 / 4), 256, 0, stream>>>(q, k, ks, vt, vst, ctx);

  // out-proj: BN=64 -> 12x32 = 384 blocks (vs 192 at BN=128) on 256 CUs
  gemm_bt<1, 64><<<dim3(768 / 64, 4096 / 128), 256, 0, stream>>>(
      ctx, w2b, outb, nullptr, nullptr, nullptr, nullptr, nullptr,
      out, 4096, 768, 768);
}

// Round 8
// 150.077 us; speedup vs baseline: 2.4396x; 1.0119x over previous
//
#include <hip/hip_runtime.h>
#include <hip/hip_bf16.h>
#include <stdint.h>

// Problem constants (UniformStrideAttention): B=2, S=2048, D=768, H=12, HD=64, STRIDE=8
#define H_   12
#define S_   2048
#define D_   768
#define HD_  64
#define MS_  256   // S_/8 compressed strided keys per head

typedef __bf16 bf16_8 __attribute__((ext_vector_type(8)));
typedef float  f32_4  __attribute__((ext_vector_type(4)));

typedef __attribute__((address_space(1))) void* gas_ptr;
typedef __attribute__((address_space(3))) void* las_ptr;

__device__ __forceinline__ void g2l16(const void* g, void* l) {
  __builtin_amdgcn_global_load_lds((gas_ptr)g, (las_ptr)l, 16, 0, 0);
}

__device__ __forceinline__ f32_4 mfma16(bf16_8 a, bf16_8 b, f32_4 c) {
  return __builtin_amdgcn_mfma_f32_16x16x32_bf16(a, b, c, 0, 0, 0);
}

__device__ __forceinline__ bf16_8 ld8(const __hip_bfloat16* p) {
  return *reinterpret_cast<const bf16_8*>(p);
}

// ---------------------------------------------------------------------------
// Fused fp32 -> bf16 convert for all three GEMM inputs (x, qkv_w, out_w).
// Destinations are CONTIGUOUS in ws (xb | w1b | w2b), so output index == t.
// ---------------------------------------------------------------------------
__global__ __launch_bounds__(256) void cvt3_f32_bf16(
    const float* __restrict__ a, const float* __restrict__ b,
    const float* __restrict__ c, __hip_bfloat16* __restrict__ out,
    int na4, int nb4) {
  const int t = blockIdx.x * 256 + threadIdx.x;
  float4 f;
  if (t < na4)            f = reinterpret_cast<const float4*>(a)[t];
  else if (t < na4 + nb4) f = reinterpret_cast<const float4*>(b)[t - na4];
  else                    f = reinterpret_cast<const float4*>(c)[t - na4 - nb4];
  union { __hip_bfloat16 h[4]; ushort4 u; } p;
  p.h[0] = __float2bfloat16(f.x);
  p.h[1] = __float2bfloat16(f.y);
  p.h[2] = __float2bfloat16(f.z);
  p.h[3] = __float2bfloat16(f.w);
  reinterpret_cast<ushort4*>(out)[t] = p.u;
}

// ---------------------------------------------------------------------------
// C[M,N] = A[M,K] * B[N,K]^T + bias[N]   (bf16 in, fp32 MFMA accum, fp32 bias)
// Tile 128 x BN, BK=32; 4 waves as 2x2 of 64 x BN/2; 16x16x32 MFMA.
// MODE 0 (BN=128): QKV epilogue -> q/k/v row-major [bh][s][d] (all coalesced;
//   no more V-transpose scatter) + compressed Ks[bh][s/8][d] (t==1, s%8==0)
//   + VsT[bh][d][s/8] (t==2, s%8==0, scalar — only 0.8 MB).
// MODE 1: plain epilogue -> OF[M,N] fp32. BN=64: 2x grid for small N.
// ---------------------------------------------------------------------------
template <int MODE, int BN>
__global__ __launch_bounds__(256, 2) void gemm_bt(
    const __hip_bfloat16* __restrict__ A, const __hip_bfloat16* __restrict__ B,
    const float* __restrict__ bias,
    __hip_bfloat16* __restrict__ O0, __hip_bfloat16* __restrict__ O1,
    __hip_bfloat16* __restrict__ O2, __hip_bfloat16* __restrict__ O3,
    __hip_bfloat16* __restrict__ O4, float* __restrict__ OF,
    int M, int N, int K) {
  constexpr int NTJ = BN / 32;          // B col-tiles per wave
  __shared__ __bf16 sA[128 * 32];
  __shared__ __bf16 sB[BN * 32];
  const int tid  = threadIdx.x;
  const int lane = tid & 63;
  const int wv   = tid >> 6;
  const int m0 = blockIdx.y * 128;
  const int n0 = blockIdx.x * BN;
  const int wr = (wv >> 1) * 64;
  const int wc = (wv & 1) * (BN / 2);

  f32_4 acc[4][NTJ] = {};

  const __hip_bfloat16* aS = A + (size_t)(m0 + (tid >> 2)) * K + ((tid & 3) << 3);
  const __hip_bfloat16* bS = B + (size_t)(n0 + (tid >> 2)) * K + ((tid & 3) << 3);
  const size_t half = (size_t)64 * K;
  __bf16* dA  = &sA[tid * 8];
  __bf16* dA2 = &sA[tid * 8 + 2048];
  __bf16* dB  = &sB[tid * 8];
  __bf16* dB2 = &sB[tid * 8 + 2048];

  const int fr = lane & 15;
  const int kq = (lane >> 4) << 3;

  for (int k0 = 0; k0 < K; k0 += 32) {
    g2l16(aS, dA);
    g2l16(aS + half, dA2);
    g2l16(bS, dB);
    if constexpr (BN == 128) g2l16(bS + half, dB2);
    aS += 32;
    bS += 32;
    __syncthreads();
    bf16_8 af[4], bfm[NTJ];
#pragma unroll
    for (int t = 0; t < 4; ++t)
      af[t] = *reinterpret_cast<const bf16_8*>(&sA[(wr + t * 16 + fr) * 32 + kq]);
#pragma unroll
    for (int t = 0; t < NTJ; ++t)
      bfm[t] = *reinterpret_cast<const bf16_8*>(&sB[(wc + t * 16 + fr) * 32 + kq]);
#pragma unroll
    for (int ti = 0; ti < 4; ++ti)
#pragma unroll
      for (int tj = 0; tj < NTJ; ++tj)
        acc[ti][tj] = mfma16(af[ti], bfm[tj], acc[ti][tj]);
    __syncthreads();
  }

  // epilogue: C/D layout col=lane&15, row=(lane>>4)*4+reg
  const int crow = (lane >> 4) << 2;
  const int ccol = lane & 15;
#pragma unroll
  for (int ti = 0; ti < 4; ++ti) {
    const int gmb = m0 + wr + ti * 16 + crow;
#pragma unroll
    for (int tj = 0; tj < NTJ; ++tj) {
      const int gn = n0 + wc + tj * 16 + ccol;
      const float bv = bias[gn];
      if (MODE == 0) {
        const int t   = gn / D_;
        const int rem = gn - t * D_;
        const int hh = rem >> 6, dd = rem & 63;
        __hip_bfloat16* dst = (t == 0) ? O0 : (t == 1) ? O1 : O2;
#pragma unroll
        for (int r = 0; r < 4; ++r) {
          const int gm = gmb + r;
          const int bb = gm >> 11, ss = gm & (S_ - 1);
          const __hip_bfloat16 hv = __float2bfloat16(acc[ti][tj][r] + bv);
          dst[(((size_t)(bb * H_ + hh) << 11) + ss) * HD_ + dd] = hv;
          if (r == 0 && (gmb & 7) == 0) {
            if (t == 1)        // compressed K rows for coalesced strided reads
              O4[(((size_t)(bb * H_ + hh)) * MS_ + (ss >> 3)) * HD_ + dd] = hv;
            else if (t == 2)   // compressed V^T (d-major) for strided PV
              O3[((size_t)(bb * H_ + hh) * HD_ + dd) * MS_ + (ss >> 3)] = hv;
          }
        }
      } else {
#pragma unroll
        for (int r = 0; r < 4; ++r)
          OF[(size_t)(gmb + r) * D_ + gn] = acc[ti][tj][r] + bv;
      }
    }
  }
}

// ---------------------------------------------------------------------------
// MFMA strided attention, NO-RESCALE softmax + chunk PREFETCH.
// mask = (j%8==0 && j<=i) | j==i | j==i-1; strided part = causal over
// compressed keys (j=8m, Ks/VsT -> fully coalesced 16B-lane reads);
// local band {i-1,i}\{mult of 8} handled after the loop: band V rows staged
// row-major->LDS at kernel start (latency hidden behind the strided loop),
// band V^T fragments built via scalar ds_read (2-way bank alias = free).
// One wave per (head, 16 query rows); per chunk 4 QK^T + 4 PV + 1 ones MFMA;
// L rides the matrix pipe (P.1); P C->A layout via per-wave LDS tile.
// ---------------------------------------------------------------------------
__global__ __launch_bounds__(256) void attn_mfma(
    const __hip_bfloat16* __restrict__ Q, const __hip_bfloat16* __restrict__ Kb,
    const __hip_bfloat16* __restrict__ Ks, const __hip_bfloat16* __restrict__ Vr,
    const __hip_bfloat16* __restrict__ VsT, __hip_bfloat16* __restrict__ ctx) {
  __shared__ __bf16 pt[4][16 * 40];
  __shared__ __bf16 vb[4][32 * 64];
  const int lane = threadIdx.x & 63;
  const int wv   = threadIdx.x >> 6;
  const int task = blockIdx.x * 4 + wv;     // 3072 tasks = bh*128 + qtile
  const int bh   = task >> 7;
  const int i0   = (task & 127) << 4;       // first of 16 query rows
  const int lr   = lane & 15;
  const int quad = lane >> 4;
  const float SC = 0.125f * 1.44269504088896340736f;  // 1/sqrt(64)*log2(e)

  const __hip_bfloat16* Kh  = Kb  + ((size_t)bh << 11) * HD_;
  const __hip_bfloat16* Ksh = Ks  + (size_t)bh * MS_ * HD_;
  const __hip_bfloat16* Vrh = Vr  + ((size_t)bh << 11) * HD_;
  const __hip_bfloat16* Vsh = VsT + (size_t)bh * HD_ * MS_;
  __bf16* ptw = pt[wv];
  __bf16* vbw = vb[wv];

  const int jbase = (i0 >= 8) ? (i0 - 8) : 0;   // local band base (8-aligned)

  // --- early: stage band V rows [jbase..jbase+32) (clamped) into LDS; these
  // global loads issue now and their latency hides behind the strided loop ---
#pragma unroll
  for (int it = 0; it < 4; ++it) {
    const int cidx = it * 64 + lane;
    const int row = cidx >> 3, seg = cidx & 7;
    const int j  = jbase + row;
    const int jr = (j < S_) ? j : (S_ - 1);       // clamp; masked via P=0
    *reinterpret_cast<bf16_8*>(vbw + row * 64 + seg * 8) =
        ld8(Vrh + (size_t)jr * HD_ + seg * 8);
  }
  // --- early: band K fragments from row-major k ---
  bf16_8 kb_[2][2];
#pragma unroll
  for (int t = 0; t < 2; ++t) {
    const int j  = jbase + t * 16 + lr;
    const int jr = (j < S_) ? j : (S_ - 1);
    const __hip_bfloat16* kp = Kh + (size_t)jr * HD_ + quad * 8;
    kb_[t][0] = ld8(kp);
    kb_[t][1] = ld8(kp + 32);
  }

  // Q A-frags: row = i0+lr, k = quad*8 (+32) — held all kernel
  const __hip_bfloat16* qp = Q + (((size_t)bh << 11) + i0 + lr) * HD_ + quad * 8;
  const bf16_8 qf0 = ld8(qp);
  const bf16_8 qf1 = ld8(qp + 32);

  const __bf16 one = (__bf16)1.0f;
  const bf16_8 onesf = {one, one, one, one, one, one, one, one};

  f32_4 Lacc = {}, oacc[4];
#pragma unroll
  for (int ct = 0; ct < 4; ++ct) oacc[ct] = f32_4{0.f, 0.f, 0.f, 0.f};

  const int mmax = (i0 + 15) >> 3;
  const int nstr = (mmax >> 5) + 1;   // strided 32-key chunks

  auto load_str = [&](int c, bf16_8 (&kf)[2][2], bf16_8 (&vf)[4]) {
    const int mb = c << 5;
#pragma unroll
    for (int t = 0; t < 2; ++t) {
      const __hip_bfloat16* kp = Ksh + (size_t)(mb + t * 16 + lr) * HD_ + quad * 8;
      kf[t][0] = ld8(kp);
      kf[t][1] = ld8(kp + 32);
    }
#pragma unroll
    for (int ct = 0; ct < 4; ++ct)
      vf[ct] = ld8(Vsh + (size_t)(ct * 16 + lr) * MS_ + mb + quad * 8);
  };

  auto softmax_pv = [&](f32_4& s0, f32_4& s1, const bf16_8 (&vf)[4]) {
    // P: C-layout -> A-layout via per-wave LDS tile; then PV and L += P.1
#pragma unroll
    for (int r = 0; r < 4; ++r) {
      const int row = quad * 4 + r;
      ptw[row * 40 + lr]      = (__bf16)__float2bfloat16(s0[r]);
      ptw[row * 40 + 16 + lr] = (__bf16)__float2bfloat16(s1[r]);
    }
    const bf16_8 pf = *reinterpret_cast<const bf16_8*>(&ptw[lr * 40 + quad * 8]);
#pragma unroll
    for (int ct = 0; ct < 4; ++ct) oacc[ct] = mfma16(pf, vf[ct], oacc[ct]);
    Lacc = mfma16(pf, onesf, Lacc);
  };

  // --- strided chunks (prefetched) ---
  bf16_8 kf[2][2], vf[4], kf2[2][2], vf2[4];
  load_str(0, kf, vf);
  for (int c = 0; c < nstr; ++c) {
    const bool more = (c + 1 < nstr);
    if (more) load_str(c + 1, kf2, vf2);
    const int mb = c << 5;

    f32_4 s0 = {}, s1 = {};
    s0 = mfma16(qf0, kf[0][0], s0);
    s0 = mfma16(qf1, kf[0][1], s0);
    s1 = mfma16(qf0, kf[1][0], s1);
    s1 = mfma16(qf1, kf[1][1], s1);

#pragma unroll
    for (int r = 0; r < 4; ++r) {
      const int i = i0 + quad * 4 + r;
      const bool v0 = ((mb + lr) << 3) <= i;
      const bool v1 = ((mb + 16 + lr) << 3) <= i;
      s0[r] = v0 ? exp2f(fminf(s0[r] * SC, 63.f)) : 0.f;
      s1[r] = v1 ? exp2f(fminf(s1[r] * SC, 63.f)) : 0.f;
    }
    softmax_pv(s0, s1, vf);

    if (more) {
#pragma unroll
      for (int t = 0; t < 2; ++t) { kf[t][0] = kf2[t][0]; kf[t][1] = kf2[t][1]; }
#pragma unroll
      for (int ct = 0; ct < 4; ++ct) vf[ct] = vf2[ct];
    }
  }

  // --- local band chunk {i-1,i} \ multiples-of-8 ---
  {
    f32_4 s0 = {}, s1 = {};
    s0 = mfma16(qf0, kb_[0][0], s0);
    s0 = mfma16(qf1, kb_[0][1], s0);
    s1 = mfma16(qf0, kb_[1][0], s1);
    s1 = mfma16(qf1, kb_[1][1], s1);

#pragma unroll
    for (int r = 0; r < 4; ++r) {
      const int i = i0 + quad * 4 + r;
      const int j0 = jbase + lr, j1 = jbase + 16 + lr;
      const bool v0 = (j0 == i || j0 == i - 1) && (j0 & 7);
      const bool v1 = (j1 == i || j1 == i - 1) && (j1 & 7);
      s0[r] = v0 ? exp2f(fminf(s0[r] * SC, 63.f)) : 0.f;
      s1[r] = v1 ? exp2f(fminf(s1[r] * SC, 63.f)) : 0.f;
    }

    // band V^T fragments from the LDS row-major tile
    bf16_8 vfb[4];
#pragma unroll
    for (int ct = 0; ct < 4; ++ct) {
      bf16_8 tmp;
#pragma unroll
      for (int e = 0; e < 8; ++e)
        tmp[e] = vbw[(quad * 8 + e) * 64 + ct * 16 + lr];
      vfb[ct] = tmp;
    }
    softmax_pv(s0, s1, vfb);
  }

  // --- epilogue: o/l -> ctx[b][s][h*64+d] ---
  const int b = bh / H_;
  const int h = bh - b * H_;
  f32_4 inv;
#pragma unroll
  for (int r = 0; r < 4; ++r) inv[r] = 1.f / Lacc[r];
#pragma unroll
  for (int r = 0; r < 4; ++r) {
    const int i = i0 + quad * 4 + r;
    __hip_bfloat16* cp = ctx + ((size_t)(b * S_ + i)) * D_ + h * HD_ + lr;
#pragma unroll
    for (int ct = 0; ct < 4; ++ct)
      cp[ct * 16] = __float2bfloat16(oacc[ct][r] * inv[r]);
  }
}

// ---------------------------------------------------------------------------
extern "C" void kernel_launch(void* const* d_in, const int* in_sizes, int n_in,
                              void* d_out, int out_size, void* d_ws, size_t ws_size,
                              hipStream_t stream) {
  const float* x    = (const float*)d_in[0];  // [B,S,D]    fp32
  const float* qkvw = (const float*)d_in[1];  // [3D,D]     fp32
  const float* qkvb = (const float*)d_in[2];  // [3D]       fp32
  const float* outw = (const float*)d_in[3];  // [D,D]      fp32
  const float* outb = (const float*)d_in[4];  // [D]        fp32
  float* out = (float*)d_out;                 // [B,S,D]    fp32

  const size_t NX  = (size_t)2 * S_ * D_;     // 3,145,728
  const size_t NW1 = (size_t)3 * D_ * D_;     // 1,769,472
  const size_t NW2 = (size_t)D_ * D_;         //   589,824
  const size_t NVS = (size_t)2 * H_ * HD_ * MS_;  // 393,216

  __hip_bfloat16* xb  = (__hip_bfloat16*)d_ws;
  __hip_bfloat16* w1b = xb + NX;
  __hip_bfloat16* w2b = w1b + NW1;
  __hip_bfloat16* q   = w2b + NW2;
  __hip_bfloat16* k   = q + NX;
  __hip_bfloat16* vr  = k + NX;     // [bh][s][d] row-major v
  __hip_bfloat16* vst = vr + NX;    // [bh][64][256] compressed V^T
  __hip_bfloat16* ks  = vst + NVS;  // [bh][256][64] compressed K rows
  __hip_bfloat16* ctx = ks + NVS;   // [B,S,H*HD]
  // total ws: (5*NX + NW1 + NW2 + 2*NVS)*2 B ~= 37.3 MB

  // fused fp32 -> bf16 converts (xb|w1b|w2b contiguous)
  const int na4 = (int)(NX / 4), nb4 = (int)(NW1 / 4), nc4 = (int)(NW2 / 4);
  cvt3_f32_bf16<<<dim3((na4 + nb4 + nc4) / 256), 256, 0, stream>>>(
      x, qkvw, outw, xb, na4, nb4);

  gemm_bt<0, 128><<<dim3(2304 / 128, 4096 / 128), 256, 0, stream>>>(
      xb, w1b, qkvb, q, k, vr, vst, ks, nullptr, 4096, 2304, 768);

  attn_mfma<<<dim3(2 * H_ * S_ / 16 / 4), 256, 0, stream>>>(q, k, ks, vr, vst, ctx);

  // out-proj: BN=64 -> 12x32 = 384 blocks (vs 192 at BN=128) on 256 CUs
  gemm_bt<1, 64><<<dim3(768 / 64, 4096 / 128), 256, 0, stream>>>(
      ctx, w2b, outb, nullptr, nullptr, nullptr, nullptr, nullptr,
      out, 4096, 768, 768);
}